// Round 10
// baseline (2584.698 us; speedup 1.0000x reference)
//
#include <hip/hip_runtime.h>
#include <algorithm>
#include <cstdint>

// Problem constants (fixed by setup_inputs)
#define Nn 8192
#define Mm 8192
#define Dd 512
#define Cc 128

#define BT  128  // tile (n and m) for both passes
#define SW2 132  // pass2 LDS row stride: 128 + 4 -> bank-rotate 4/row:
                 // scalar staging writes 2-way (free), b128 reads clean
#define TK  16   // k-chunk (load-bearing for numerics; do not change)

// Register-allocator ledger (this session, gfx950 ROCm): RA targets ~2x the
// declared min-waves/EU and spills to reach it.
//   (256,2) -> 128 VGPR (good) ; (256,3) -> 84+spill ; (512,2) -> 56+spill ;
//   waves_per_eu(3,3) -> 84 + 11.5 GB thrash.
// Pass1 (256 thr, live ~115): (256,2). Pass2 (512 thr, live ~110): (512,1)
// -> expected budget ~256 VGPR (2 waves/EU target), ample.
#define KERNEL_OCC1 __launch_bounds__(256, 2)
#define KERNEL_OCC2 __launch_bounds__(512, 1)

// ---- workspace layout (bytes) ----
#define WS_SR    0ull         // double[8192]
#define WS_SC    65536ull     // double[8192]
#define WS_CTR   131072ull    // uint[16]: 0=cand_n 1=fin_n 2=run_tb16 3=tb16 4=cbin 5=above
#define WS_GHC   131136ull    // uint[256] coarse hist
#define WS_GHF   132160ull    // uint[256] fine hist
#define WS_FINAL 133184ull    // uint2[4096]
#define WS_CAND  165952ull    // uint2[cap]
#define FCAP     4096u

// column mapping (8 cols over 128): {tx*4..+3} and {64+tx*4..+3}
__device__ __forceinline__ int jcol(int tx, int j) {
  return (j < 4) ? tx * 4 + j : 64 + tx * 4 + (j - 4);
}

// ---------------------------------------------------------------------------
// Pass-1 inner GEMM (256 thr, 8x8/thread), two-level accumulation with i-split.
// Per-element chain: fresh 16-fma chain per 16-k chunk (kk order), one add into
// acc2, chunks in order. Proven absmax=0 (R4-R9). ~87% of fp32 roofline.
// ---------------------------------------------------------------------------
__device__ __forceinline__ void inner_gemm(const float* __restrict__ A,
                                           const float* __restrict__ B,
                                           int n0, int m0, int tid,
                                           float (*SA)[BT], float (*SB)[BT],
                                           float acc2[8][8]) {
  const int tx = tid & 15, ty = tid >> 4;
  const int lrow = tid >> 1;       // 0..127
  const int lk8  = (tid & 1) * 8;  // 0 or 8
  const float* Ap = A + (size_t)(n0 + lrow) * Dd + lk8;
  const float* Bp = B + (size_t)(m0 + lrow) * Dd + lk8;

#pragma unroll
  for (int i = 0; i < 8; ++i)
#pragma unroll
    for (int j = 0; j < 8; ++j) acc2[i][j] = 0.0f;

  float4 pa0 = *(const float4*)(Ap);
  float4 pa1 = *(const float4*)(Ap + 4);
  float4 pb0 = *(const float4*)(Bp);
  float4 pb1 = *(const float4*)(Bp + 4);

  for (int k0 = 0; k0 < Dd; k0 += TK) {
    __syncthreads();
    {
      const float ar[8] = {pa0.x,pa0.y,pa0.z,pa0.w,pa1.x,pa1.y,pa1.z,pa1.w};
      const float br[8] = {pb0.x,pb0.y,pb0.z,pb0.w,pb1.x,pb1.y,pb1.z,pb1.w};
#pragma unroll
      for (int s = 0; s < 8; ++s) { SA[lk8 + s][lrow] = ar[s]; SB[lk8 + s][lrow] = br[s]; }
    }
    if (k0 + TK < Dd) {  // prefetch flies during compute
      pa0 = *(const float4*)(Ap + k0 + TK);
      pa1 = *(const float4*)(Ap + k0 + TK + 4);
      pb0 = *(const float4*)(Bp + k0 + TK);
      pb1 = *(const float4*)(Bp + k0 + TK + 4);
    }
    __syncthreads();
#pragma unroll
    for (int h = 0; h < 2; ++h) {
      float t[4][8];
#pragma unroll
      for (int i = 0; i < 4; ++i)
#pragma unroll
        for (int j = 0; j < 8; ++j) t[i][j] = 0.0f;
#pragma unroll
      for (int kk = 0; kk < TK; ++kk) {
        const float4 av  = *(const float4*)&SA[kk][ty * 8 + h * 4];
        const float4 bv0 = *(const float4*)&SB[kk][tx * 4];
        const float4 bv1 = *(const float4*)&SB[kk][64 + tx * 4];
        const float a[4] = {av.x, av.y, av.z, av.w};
        const float b[8] = {bv0.x,bv0.y,bv0.z,bv0.w,bv1.x,bv1.y,bv1.z,bv1.w};
#pragma unroll
        for (int i = 0; i < 4; ++i)
#pragma unroll
          for (int j = 0; j < 8; ++j) t[i][j] = fmaf(a[i], b[j], t[i][j]);
      }
#pragma unroll
      for (int i = 0; i < 4; ++i)
#pragma unroll
        for (int j = 0; j < 8; ++j) acc2[h * 4 + i][j] += t[i][j];
    }
  }
}

// ---------------------------------------------------------------------------
// Pass 1: inner GEMM -> exp row/col sums (f64).
// ---------------------------------------------------------------------------
__global__ KERNEL_OCC1 void k_pass1(const float* __restrict__ A,
                                    const float* __restrict__ B,
                                    double* __restrict__ Sr,
                                    double* __restrict__ Sc) {
  __shared__ float SA[TK][BT];
  __shared__ float SB[TK][BT];
  __shared__ double csum[BT];
  const int tid = threadIdx.x;
  const int tx = tid & 15, ty = tid >> 4;
  const int n0 = blockIdx.y * BT, m0 = blockIdx.x * BT;

  float acc2[8][8];
  inner_gemm(A, B, n0, m0, tid, SA, SB, acc2);

  if (tid < BT) csum[tid] = 0.0;
  __syncthreads();

  float cp[8];
#pragma unroll
  for (int j = 0; j < 8; ++j) cp[j] = 0.0f;

#pragma unroll
  for (int i = 0; i < 8; ++i) {
    float r = 0.0f;
#pragma unroll
    for (int j = 0; j < 8; ++j) {
      const float e = expf(2.0f * acc2[i][j] - 2.0f);
      r += e;
      cp[j] += e;
    }
    double v = (double)r;
    v += __shfl_xor(v, 1, 16);
    v += __shfl_xor(v, 2, 16);
    v += __shfl_xor(v, 4, 16);
    v += __shfl_xor(v, 8, 16);
    if (tx == 0) atomicAdd(&Sr[n0 + ty * 8 + i], v);
  }
#pragma unroll
  for (int j = 0; j < 8; ++j) {
    double v = (double)cp[j];
    v += __shfl_xor(v, 16, 64);
    v += __shfl_xor(v, 32, 64);
    if ((tid & 63) < 16) atomicAdd(&csum[jcol(tx, j)], v);
  }
  __syncthreads();
  if (tid < BT) atomicAdd(&Sc[m0 + tid], csum[tid]);
}

// ---------------------------------------------------------------------------
__global__ void k_recip(double* __restrict__ Sr, double* __restrict__ Sc) {
  const int i = blockIdx.x * 256 + threadIdx.x;
  if (i < Nn) Sr[i] = 1.0 / Sr[i];
  if (i < Mm) Sc[i] = 1.0 / Sc[i];
}

// ---------------------------------------------------------------------------
// Pass 2: 128x128 tile, 512 thr, 4x8/thread (tx=tid&15, ty=tid>>4 in 0..31).
// Half the blocks of R9 -> half the per-FLOP barrier/epilogue overhead.
// Live regs ~110 (acc2 32 + ov2 32 + t 32 transient + staging/addr).
// Per-element FP chains identical to R8/R9 -> same score bits -> absmax 0.
// ---------------------------------------------------------------------------
__global__ KERNEL_OCC2 void k_pass2(
    const float* __restrict__ A, const float* __restrict__ B,
    const float* __restrict__ C0, const float* __restrict__ C1,
    const double* __restrict__ invSr, const double* __restrict__ invSc,
    uint2* __restrict__ cand, unsigned int* __restrict__ ctr, unsigned int cap) {
  __shared__ float SA[TK][SW2];
  __shared__ float SB[TK][SW2];
  __shared__ unsigned int h1[256];
  __shared__ unsigned int wsum[8];   // per-wave scan sums
  __shared__ unsigned int sh_misc[4];
  const int tid = threadIdx.x;
  const int tx = tid & 15, ty = tid >> 4;   // 16 x 32 thread grid, 4 rows x 8 cols
  const int n0 = blockIdx.y * BT, m0 = blockIdx.x * BT;

  // ---- inner GEMM (two-level, t[4][8] per chunk) ----
  float acc2[4][8];
#pragma unroll
  for (int i = 0; i < 4; ++i)
#pragma unroll
    for (int j = 0; j < 8; ++j) acc2[i][j] = 0.0f;
  {
    const int lrow = tid >> 2;       // 0..127
    const int lk4  = (tid & 3) * 4;  // 0,4,8,12
    const float* Ap = A + (size_t)(n0 + lrow) * Dd + lk4;
    const float* Bp = B + (size_t)(m0 + lrow) * Dd + lk4;
    float4 pa = *(const float4*)(Ap);
    float4 pb = *(const float4*)(Bp);
    for (int k0 = 0; k0 < Dd; k0 += TK) {
      __syncthreads();
      SA[lk4 + 0][lrow] = pa.x; SA[lk4 + 1][lrow] = pa.y;
      SA[lk4 + 2][lrow] = pa.z; SA[lk4 + 3][lrow] = pa.w;
      SB[lk4 + 0][lrow] = pb.x; SB[lk4 + 1][lrow] = pb.y;
      SB[lk4 + 2][lrow] = pb.z; SB[lk4 + 3][lrow] = pb.w;
      if (k0 + TK < Dd) {
        pa = *(const float4*)(Ap + k0 + TK);
        pb = *(const float4*)(Bp + k0 + TK);
      }
      __syncthreads();
      float t[4][8];
#pragma unroll
      for (int i = 0; i < 4; ++i)
#pragma unroll
        for (int j = 0; j < 8; ++j) t[i][j] = 0.0f;
#pragma unroll
      for (int kk = 0; kk < TK; ++kk) {
        const float4 av  = *(const float4*)&SA[kk][ty * 4];
        const float4 bv0 = *(const float4*)&SB[kk][tx * 4];
        const float4 bv1 = *(const float4*)&SB[kk][64 + tx * 4];
        const float a[4] = {av.x, av.y, av.z, av.w};
        const float b[8] = {bv0.x,bv0.y,bv0.z,bv0.w,bv1.x,bv1.y,bv1.z,bv1.w};
#pragma unroll
        for (int i = 0; i < 4; ++i)
#pragma unroll
          for (int j = 0; j < 8; ++j) t[i][j] = fmaf(a[i], b[j], t[i][j]);
      }
#pragma unroll
      for (int i = 0; i < 4; ++i)
#pragma unroll
        for (int j = 0; j < 8; ++j) acc2[i][j] += t[i][j];
    }
  }

  // ---- overlap GEMM (cas0:[C][N] x cas1:[C][M]) ----
  float ov2[4][8];
#pragma unroll
  for (int i = 0; i < 4; ++i)
#pragma unroll
    for (int j = 0; j < 8; ++j) ov2[i][j] = 0.0f;
  {
    const int frow = tid >> 5;        // 0..15
    const int fn   = (tid & 31) * 4;  // 0..124
    const float* c0p = C0 + (size_t)frow * Nn + n0 + fn;
    const float* c1p = C1 + (size_t)frow * Mm + m0 + fn;
    float4 pa = *(const float4*)c0p;
    float4 pb = *(const float4*)c1p;
    for (int c0i = 0; c0i < Cc; c0i += TK) {
      __syncthreads();
      *(float4*)&SA[frow][fn] = pa;
      *(float4*)&SB[frow][fn] = pb;
      if (c0i + TK < Cc) {
        pa = *(const float4*)(c0p + (size_t)(c0i + TK) * Nn);
        pb = *(const float4*)(c1p + (size_t)(c0i + TK) * Mm);
      }
      __syncthreads();
      float t[4][8];
#pragma unroll
      for (int i = 0; i < 4; ++i)
#pragma unroll
        for (int j = 0; j < 8; ++j) t[i][j] = 0.0f;
#pragma unroll
      for (int kk = 0; kk < TK; ++kk) {
        const float4 av  = *(const float4*)&SA[kk][ty * 4];
        const float4 bv0 = *(const float4*)&SB[kk][tx * 4];
        const float4 bv1 = *(const float4*)&SB[kk][64 + tx * 4];
        const float a[4] = {av.x, av.y, av.z, av.w};
        const float b[8] = {bv0.x,bv0.y,bv0.z,bv0.w,bv1.x,bv1.y,bv1.z,bv1.w};
#pragma unroll
        for (int i = 0; i < 4; ++i)
#pragma unroll
          for (int j = 0; j < 8; ++j) t[i][j] = fmaf(a[i], b[j], t[i][j]);
      }
#pragma unroll
      for (int i = 0; i < 4; ++i)
#pragma unroll
        for (int j = 0; j < 8; ++j) ov2[i][j] += t[i][j];
    }
  }

  // ---- f64 normalizers via LDS (same bits), f64 score -> f32 key ----
  __syncthreads();
  double* dsr = (double*)(&SA[0][0]);   // 128 doubles
  double* dsc = (double*)(&SB[0][0]);   // 128 doubles
  if (tid < BT) { dsr[tid] = invSr[n0 + tid]; dsc[tid] = invSc[m0 + tid]; }
  __syncthreads();

  unsigned int sbits[4][8];
#pragma unroll
  for (int i = 0; i < 4; ++i)
#pragma unroll
    for (int j = 0; j < 8; ++j) {
      const double e = exp(2.0 * (double)acc2[i][j] - 2.0);
      const double s = e * e * dsr[ty * 4 + i] * dsc[jcol(tx, j)] * (double)ov2[i][j];
      sbits[i][j] = __float_as_uint((float)s);  // s > 0 -> monotone bits
    }

  // ---- two-level (8+8 bit) block histogram threshold over 16384 elems ----
  if (tid < 256) h1[tid] = 0;
  __syncthreads();
#pragma unroll
  for (int i = 0; i < 4; ++i)
#pragma unroll
    for (int j = 0; j < 8; ++j) atomicAdd(&h1[sbits[i][j] >> 24], 1u);
  __syncthreads();
  if (tid == 0) {
    unsigned cum = 0, cb = 0, above = 0;
    for (int b = 255; b >= 0; --b) {
      const unsigned nc = cum + h1[b];
      if (nc >= 256u) { cb = (unsigned)b; above = cum; break; }
      cum = nc;
    }
    sh_misc[0] = cb; sh_misc[1] = above;
  }
  __syncthreads();
  const unsigned cb = sh_misc[0], above = sh_misc[1];
  __syncthreads();
  if (tid < 256) h1[tid] = 0;
  __syncthreads();
#pragma unroll
  for (int i = 0; i < 4; ++i)
#pragma unroll
    for (int j = 0; j < 8; ++j)
      if ((sbits[i][j] >> 24) == cb) atomicAdd(&h1[(sbits[i][j] >> 16) & 0xFFu], 1u);
  __syncthreads();
  if (tid == 0) {
    unsigned cum = above, tb = cb << 8;
    for (int b = 255; b >= 0; --b) {
      cum += h1[b];
      if (cum >= 256u) { tb = (cb << 8) | (unsigned)b; break; }
    }
    const unsigned old = atomicMax(&ctr[2], tb);  // device-scope running bound
    sh_misc[2] = tb > old ? tb : old;
  }
  __syncthreads();
  const unsigned tb16 = sh_misc[2];

  // ---- candidate push: shuffle-based wave scan + 8-entry serial base ----
  unsigned cnt = 0;
#pragma unroll
  for (int i = 0; i < 4; ++i)
#pragma unroll
    for (int j = 0; j < 8; ++j) cnt += ((sbits[i][j] >> 16) >= tb16) ? 1u : 0u;
  const int lane = tid & 63, wv = tid >> 6;
  unsigned incl = cnt;
#pragma unroll
  for (int d = 1; d < 64; d <<= 1) {
    const unsigned nv = __shfl_up(incl, d, 64);
    if (lane >= d) incl += nv;
  }
  if (lane == 63) wsum[wv] = incl;   // wave total
  __syncthreads();
  if (tid == 0) {
    unsigned run = 0;
#pragma unroll
    for (int w = 0; w < 8; ++w) { const unsigned c = wsum[w]; wsum[w] = run; run += c; }
    sh_misc[3] = atomicAdd(&ctr[0], run);
  }
  __syncthreads();
  unsigned pos = sh_misc[3] + wsum[wv] + incl - cnt;
#pragma unroll
  for (int i = 0; i < 4; ++i)
#pragma unroll
    for (int j = 0; j < 8; ++j) {
      if ((sbits[i][j] >> 16) >= tb16) {
        if (pos < cap) {
          const unsigned idxv = ((unsigned)(n0 + ty * 4 + i) << 13) | (unsigned)(m0 + jcol(tx, j));
          cand[pos] = make_uint2(sbits[i][j], idxv);
        }
        ++pos;
      }
    }
}

// ---------------------------------------------------------------------------
// Tail: LDS-aggregated coarse(8b) + fine(8b) histograms -> threshold -> collect
// -> sort.
// ---------------------------------------------------------------------------
__global__ __launch_bounds__(256) void k_histc(const uint2* __restrict__ cand,
                                               const unsigned int* __restrict__ ctr,
                                               unsigned int cap,
                                               unsigned int* __restrict__ ghc) {
  __shared__ unsigned int lh[256];
  const int tid = threadIdx.x;
  lh[tid] = 0;
  __syncthreads();
  const unsigned n = min(ctr[0], cap);
  const unsigned stride = gridDim.x * blockDim.x;
  for (unsigned i = blockIdx.x * blockDim.x + tid; i < n; i += stride)
    atomicAdd(&lh[cand[i].x >> 24], 1u);
  __syncthreads();
  if (lh[tid]) atomicAdd(&ghc[tid], lh[tid]);
}

__global__ __launch_bounds__(256) void k_threshc(const unsigned int* __restrict__ ghc,
                                                 unsigned int* __restrict__ ctr) {
  __shared__ unsigned int g[256];
  const int tid = threadIdx.x;
  g[tid] = ghc[tid];
  __syncthreads();
  if (tid == 0) {
    unsigned cum = 0;
    for (int b = 255; b >= 0; --b) {
      cum += g[b];
      if (cum >= 256u) { ctr[4] = (unsigned)b; ctr[5] = cum - g[b]; break; }
    }
  }
}

__global__ __launch_bounds__(256) void k_histf(const uint2* __restrict__ cand,
                                               const unsigned int* __restrict__ ctr,
                                               unsigned int cap,
                                               unsigned int* __restrict__ ghf) {
  __shared__ unsigned int lh[256];
  const int tid = threadIdx.x;
  lh[tid] = 0;
  __syncthreads();
  const unsigned n = min(ctr[0], cap);
  const unsigned cb = ctr[4];
  const unsigned stride = gridDim.x * blockDim.x;
  for (unsigned i = blockIdx.x * blockDim.x + tid; i < n; i += stride) {
    const unsigned k = cand[i].x;
    if ((k >> 24) == cb) atomicAdd(&lh[(k >> 16) & 0xFFu], 1u);
  }
  __syncthreads();
  if (lh[tid]) atomicAdd(&ghf[tid], lh[tid]);
}

__global__ __launch_bounds__(256) void k_threshf(const unsigned int* __restrict__ ghf,
                                                 unsigned int* __restrict__ ctr) {
  __shared__ unsigned int g[256];
  const int tid = threadIdx.x;
  g[tid] = ghf[tid];
  __syncthreads();
  if (tid == 0) {
    const unsigned cb = ctr[4];
    unsigned cum = ctr[5], tb = cb << 8;
    for (int b = 255; b >= 0; --b) {
      cum += g[b];
      if (cum >= 256u) { tb = (cb << 8) | (unsigned)b; break; }
    }
    ctr[3] = tb;
  }
}

__global__ void k_collect(const uint2* __restrict__ cand,
                          unsigned int* __restrict__ ctr,
                          unsigned int cap, uint2* __restrict__ fin) {
  const unsigned n = min(ctr[0], cap);
  const unsigned tb = ctr[3];
  const unsigned stride = gridDim.x * blockDim.x;
  for (unsigned i = blockIdx.x * blockDim.x + threadIdx.x; i < n; i += stride) {
    const uint2 c = cand[i];
    if ((c.x >> 16) >= tb) {
      const unsigned p = atomicAdd(&ctr[1], 1u);
      if (p < FCAP) fin[p] = c;
    }
  }
}

// Sort: pack (key, ~idx) into u64, bitonic desc -> (key desc, idx asc) —
// exactly lax.top_k / np tie semantics on the f32 scores.
__global__ __launch_bounds__(256) void k_sort(const uint2* __restrict__ fin,
                                              const unsigned int* __restrict__ ctr,
                                              float* __restrict__ out) {
  __shared__ unsigned long long kk[FCAP];
  const int tid = threadIdx.x;
  const unsigned n = min(ctr[1], FCAP);
  unsigned np2 = 256;
  while (np2 < n) np2 <<= 1;
  for (unsigned i = tid; i < np2; i += 256) {
    if (i < n) {
      const uint2 c = fin[i];
      kk[i] = ((unsigned long long)c.x << 32) | (unsigned long long)(c.y ^ 0xFFFFFFFFu);
    } else {
      kk[i] = 0ull;
    }
  }
  __syncthreads();
  for (unsigned k2 = 2; k2 <= np2; k2 <<= 1) {
    for (unsigned j = k2 >> 1; j > 0; j >>= 1) {
      for (unsigned i = tid; i < np2; i += 256) {
        const unsigned l = i ^ j;
        if (l > i) {
          const unsigned long long ka = kk[i], kb = kk[l];
          const bool aBefore = ka > kb;
          const bool dsc = (i & k2) == 0;
          const bool sw = dsc ? !aBefore : aBefore;
          if (sw) { kk[i] = kb; kk[l] = ka; }
        }
      }
      __syncthreads();
    }
  }
  {
    const unsigned long long kv = kk[tid];
    const unsigned key = (unsigned)(kv >> 32);
    const unsigned ix  = ((unsigned)kv) ^ 0xFFFFFFFFu;
    out[tid]        = (float)(ix >> 13);      // ref_corr_indices
    out[256 + tid]  = (float)(ix & 8191u);    // src_corr_indices
    out[512 + tid]  = __uint_as_float(key);   // corr_scores (same f32 bits)
  }
}

// ---------------------------------------------------------------------------
extern "C" void kernel_launch(void* const* d_in, const int* in_sizes, int n_in,
                              void* d_out, int out_size, void* d_ws, size_t ws_size,
                              hipStream_t stream) {
  (void)in_sizes; (void)n_in; (void)out_size;
  const float* ref = (const float*)d_in[0];
  const float* src = (const float*)d_in[1];
  const float* c0  = (const float*)d_in[2];
  const float* c1  = (const float*)d_in[3];
  char* ws = (char*)d_ws;
  double* Sr = (double*)(ws + WS_SR);
  double* Sc = (double*)(ws + WS_SC);
  unsigned int* ctr = (unsigned int*)(ws + WS_CTR);
  unsigned int* ghc = (unsigned int*)(ws + WS_GHC);
  unsigned int* ghf = (unsigned int*)(ws + WS_GHF);
  uint2* fin  = (uint2*)(ws + WS_FINAL);
  uint2* cand = (uint2*)(ws + WS_CAND);
  const unsigned int cap = (ws_size > WS_CAND + 8)
      ? (unsigned int)std::min<size_t>((ws_size - WS_CAND) / 8, (size_t)(16u << 20))
      : 0u;

  hipMemsetAsync(d_ws, 0, (size_t)WS_FINAL, stream);  // Sr, Sc, ctr, ghc, ghf

  dim3 g1(Mm / BT, Nn / BT);
  k_pass1<<<g1, 256, 0, stream>>>(ref, src, Sr, Sc);
  k_recip<<<32, 256, 0, stream>>>(Sr, Sc);
  k_pass2<<<g1, 512, 0, stream>>>(ref, src, c0, c1, Sr, Sc, cand, ctr, cap);
  k_histc<<<256, 256, 0, stream>>>(cand, ctr, cap, ghc);
  k_threshc<<<1, 256, 0, stream>>>(ghc, ctr);
  k_histf<<<256, 256, 0, stream>>>(cand, ctr, cap, ghf);
  k_threshf<<<1, 256, 0, stream>>>(ghf, ctr);
  k_collect<<<256, 256, 0, stream>>>(cand, ctr, cap, fin);
  k_sort<<<1, 256, 0, stream>>>(fin, ctr, (float*)d_out);
}

// Round 11
// 2543.795 us; speedup vs baseline: 1.0161x; 1.0161x over previous
//
#include <hip/hip_runtime.h>
#include <algorithm>
#include <cstdint>

// Problem constants (fixed by setup_inputs)
#define Nn 8192
#define Mm 8192
#define Dd 512
#define Cc 128

#define BT  128  // tile (n and m) for both passes
#define TK  16   // k-chunk (load-bearing for numerics; do not change)

// Register-allocator ledger (gfx950, this session): (256,2) -> 128 VGPR
// deterministic, no spills when live < 128. Every other setting tried
// ((256,3),(512,2),(512,1),waves_per_eu) under-allocates or drifts.
#define KERNEL_OCC __launch_bounds__(256, 2)

// ---- workspace layout (bytes) ----
#define WS_SR    0ull         // double[8192]
#define WS_SC    65536ull     // double[8192]
#define WS_CTR   131072ull    // uint[16]: 0=cand_n 1=fin_n 2=run_tb16 3=tb16 4=cbin 5=above
#define WS_GHC   131136ull    // uint[256] coarse hist
#define WS_GHF   132160ull    // uint[256] fine hist
#define WS_FINAL 133184ull    // uint2[4096]
#define WS_CAND  165952ull    // uint2[cap]
#define FCAP     4096u

// column mapping (8 cols over 128): {tx*4..+3} and {64+tx*4..+3}
__device__ __forceinline__ int jcol(int tx, int j) {
  return (j < 4) ? tx * 4 + j : 64 + tx * 4 + (j - 4);
}

// ---------------------------------------------------------------------------
// THE inner GEMM (256 thr, 8x8/thread, 128^2 tile): two-level accumulation
// with i-split (t is 32 regs), register prefetch. Measured ~80% of the fp32
// roofline inside k_pass1. Shared verbatim by both passes.
// Per-element chain: fresh 16-fma chain per 16-k chunk (kk order), one add
// into acc2, chunks in order. Proven absmax=0 (R4-R10).
// ---------------------------------------------------------------------------
__device__ __forceinline__ void inner_gemm(const float* __restrict__ A,
                                           const float* __restrict__ B,
                                           int n0, int m0, int tid,
                                           float (*SA)[BT], float (*SB)[BT],
                                           float acc2[8][8]) {
  const int tx = tid & 15, ty = tid >> 4;
  const int lrow = tid >> 1;       // 0..127
  const int lk8  = (tid & 1) * 8;  // 0 or 8
  const float* Ap = A + (size_t)(n0 + lrow) * Dd + lk8;
  const float* Bp = B + (size_t)(m0 + lrow) * Dd + lk8;

#pragma unroll
  for (int i = 0; i < 8; ++i)
#pragma unroll
    for (int j = 0; j < 8; ++j) acc2[i][j] = 0.0f;

  float4 pa0 = *(const float4*)(Ap);
  float4 pa1 = *(const float4*)(Ap + 4);
  float4 pb0 = *(const float4*)(Bp);
  float4 pb1 = *(const float4*)(Bp + 4);

  for (int k0 = 0; k0 < Dd; k0 += TK) {
    __syncthreads();
    {
      const float ar[8] = {pa0.x,pa0.y,pa0.z,pa0.w,pa1.x,pa1.y,pa1.z,pa1.w};
      const float br[8] = {pb0.x,pb0.y,pb0.z,pb0.w,pb1.x,pb1.y,pb1.z,pb1.w};
#pragma unroll
      for (int s = 0; s < 8; ++s) { SA[lk8 + s][lrow] = ar[s]; SB[lk8 + s][lrow] = br[s]; }
    }
    if (k0 + TK < Dd) {  // prefetch flies during compute
      pa0 = *(const float4*)(Ap + k0 + TK);
      pa1 = *(const float4*)(Ap + k0 + TK + 4);
      pb0 = *(const float4*)(Bp + k0 + TK);
      pb1 = *(const float4*)(Bp + k0 + TK + 4);
    }
    __syncthreads();
#pragma unroll
    for (int h = 0; h < 2; ++h) {
      float t[4][8];
#pragma unroll
      for (int i = 0; i < 4; ++i)
#pragma unroll
        for (int j = 0; j < 8; ++j) t[i][j] = 0.0f;
#pragma unroll
      for (int kk = 0; kk < TK; ++kk) {
        const float4 av  = *(const float4*)&SA[kk][ty * 8 + h * 4];
        const float4 bv0 = *(const float4*)&SB[kk][tx * 4];
        const float4 bv1 = *(const float4*)&SB[kk][64 + tx * 4];
        const float a[4] = {av.x, av.y, av.z, av.w};
        const float b[8] = {bv0.x,bv0.y,bv0.z,bv0.w,bv1.x,bv1.y,bv1.z,bv1.w};
#pragma unroll
        for (int i = 0; i < 4; ++i)
#pragma unroll
          for (int j = 0; j < 8; ++j) t[i][j] = fmaf(a[i], b[j], t[i][j]);
      }
#pragma unroll
      for (int i = 0; i < 4; ++i)
#pragma unroll
        for (int j = 0; j < 8; ++j) acc2[h * 4 + i][j] += t[i][j];
    }
  }
}

// ---------------------------------------------------------------------------
// Pass 1: inner GEMM -> exp row/col sums (f64). Unchanged (near roofline).
// ---------------------------------------------------------------------------
__global__ KERNEL_OCC void k_pass1(const float* __restrict__ A,
                                   const float* __restrict__ B,
                                   double* __restrict__ Sr,
                                   double* __restrict__ Sc) {
  __shared__ float SA[TK][BT];
  __shared__ float SB[TK][BT];
  __shared__ double csum[BT];
  const int tid = threadIdx.x;
  const int tx = tid & 15, ty = tid >> 4;
  const int n0 = blockIdx.y * BT, m0 = blockIdx.x * BT;

  float acc2[8][8];
  inner_gemm(A, B, n0, m0, tid, SA, SB, acc2);

  if (tid < BT) csum[tid] = 0.0;
  __syncthreads();

  float cp[8];
#pragma unroll
  for (int j = 0; j < 8; ++j) cp[j] = 0.0f;

#pragma unroll
  for (int i = 0; i < 8; ++i) {
    float r = 0.0f;
#pragma unroll
    for (int j = 0; j < 8; ++j) {
      const float e = expf(2.0f * acc2[i][j] - 2.0f);
      r += e;
      cp[j] += e;
    }
    double v = (double)r;
    v += __shfl_xor(v, 1, 16);
    v += __shfl_xor(v, 2, 16);
    v += __shfl_xor(v, 4, 16);
    v += __shfl_xor(v, 8, 16);
    if (tx == 0) atomicAdd(&Sr[n0 + ty * 8 + i], v);
  }
#pragma unroll
  for (int j = 0; j < 8; ++j) {
    double v = (double)cp[j];
    v += __shfl_xor(v, 16, 64);
    v += __shfl_xor(v, 32, 64);
    if ((tid & 63) < 16) atomicAdd(&csum[jcol(tx, j)], v);
  }
  __syncthreads();
  if (tid < BT) atomicAdd(&Sc[m0 + tid], csum[tid]);
}

// ---------------------------------------------------------------------------
__global__ void k_recip(double* __restrict__ Sr, double* __restrict__ Sc) {
  const int i = blockIdx.x * 256 + threadIdx.x;
  if (i < Nn) Sr[i] = 1.0 / Sr[i];
  if (i < Mm) Sc[i] = 1.0 / Sc[i];
}

// ---------------------------------------------------------------------------
// Pass 2: pass1's EXACT inner GEMM (shared fn), then overlap GEMM + f64
// epilogue + histogram threshold + push processed in two 128x64 COLUMN HALVES
// so live regs stay under the 128 budget (acc2 64 + ov 32 + th 16 ~ 124 peak).
// Per-half top-256 threshold remains a superset of the global top-256 within
// the half. Per-element FP chains identical to R10 -> same score bits.
// ---------------------------------------------------------------------------
__global__ KERNEL_OCC void k_pass2(
    const float* __restrict__ A, const float* __restrict__ B,
    const float* __restrict__ C0, const float* __restrict__ C1,
    const double* __restrict__ invSr, const double* __restrict__ invSc,
    uint2* __restrict__ cand, unsigned int* __restrict__ ctr, unsigned int cap) {
  __shared__ float SA[TK][BT];
  __shared__ float SB[TK][BT];
  __shared__ unsigned int h1[256];
  __shared__ unsigned int wsum[4];
  __shared__ unsigned int sh_misc[4];
  __shared__ double dsr[BT];   // dedicated (SA/SB live across halves)
  __shared__ double dsc[BT];
  const int tid = threadIdx.x;
  const int tx = tid & 15, ty = tid >> 4;
  const int n0 = blockIdx.y * BT, m0 = blockIdx.x * BT;

  // f64 normalizers -> LDS once (same bits); visible after first GEMM barrier
  if (tid < BT) dsr[tid] = invSr[n0 + tid];
  else          dsc[tid - BT] = invSc[m0 + tid - BT];

  float acc2[8][8];
  inner_gemm(A, B, n0, m0, tid, SA, SB, acc2);

  const int frow = tid >> 4;        // 0..15 overlap staging row
  const int fn   = (tid & 15) * 8;  // 0..120 staging col

#pragma unroll
  for (int h = 0; h < 2; ++h) {
    // ---- overlap GEMM for column half h (cols h*64 + tx*4 ..+3) ----
    float ov[8][4];
#pragma unroll
    for (int i = 0; i < 8; ++i)
#pragma unroll
      for (int j = 0; j < 4; ++j) ov[i][j] = 0.0f;
    for (int c0i = 0; c0i < Cc; c0i += TK) {
      __syncthreads();
      *(float4*)&SA[frow][fn]     = *(const float4*)(C0 + (size_t)(c0i + frow) * Nn + n0 + fn);
      *(float4*)&SA[frow][fn + 4] = *(const float4*)(C0 + (size_t)(c0i + frow) * Nn + n0 + fn + 4);
      *(float4*)&SB[frow][fn]     = *(const float4*)(C1 + (size_t)(c0i + frow) * Mm + m0 + fn);
      *(float4*)&SB[frow][fn + 4] = *(const float4*)(C1 + (size_t)(c0i + frow) * Mm + m0 + fn + 4);
      __syncthreads();
#pragma unroll
      for (int g = 0; g < 2; ++g) {
        float th[4][4];
#pragma unroll
        for (int i = 0; i < 4; ++i)
#pragma unroll
          for (int j = 0; j < 4; ++j) th[i][j] = 0.0f;
#pragma unroll
        for (int kk = 0; kk < TK; ++kk) {
          const float4 av = *(const float4*)&SA[kk][ty * 8 + g * 4];
          const float4 bv = *(const float4*)&SB[kk][h * 64 + tx * 4];
          const float a[4] = {av.x, av.y, av.z, av.w};
          const float b[4] = {bv.x, bv.y, bv.z, bv.w};
#pragma unroll
          for (int i = 0; i < 4; ++i)
#pragma unroll
            for (int j = 0; j < 4; ++j) th[i][j] = fmaf(a[i], b[j], th[i][j]);
        }
#pragma unroll
        for (int i = 0; i < 4; ++i)
#pragma unroll
          for (int j = 0; j < 4; ++j) ov[g * 4 + i][j] += th[i][j];
      }
    }

    // ---- f64 score -> f32 key bits (ov dies into sb) ----
    unsigned int sb[8][4];
#pragma unroll
    for (int i = 0; i < 8; ++i)
#pragma unroll
      for (int j = 0; j < 4; ++j) {
        const double e = exp(2.0 * (double)acc2[i][h * 4 + j] - 2.0);
        const double s = e * e * dsr[ty * 8 + i] * dsc[h * 64 + tx * 4 + j] * (double)ov[i][j];
        sb[i][j] = __float_as_uint((float)s);  // s > 0 -> monotone bits
      }

    // ---- two-level (8+8 bit) histogram threshold over this half (8192) ----
    __syncthreads();
    h1[tid] = 0;
    __syncthreads();
#pragma unroll
    for (int i = 0; i < 8; ++i)
#pragma unroll
      for (int j = 0; j < 4; ++j) atomicAdd(&h1[sb[i][j] >> 24], 1u);
    __syncthreads();
    if (tid == 0) {
      unsigned cum = 0, cb2 = 0, abv = 0;
      for (int b = 255; b >= 0; --b) {
        const unsigned nc = cum + h1[b];
        if (nc >= 256u) { cb2 = (unsigned)b; abv = cum; break; }
        cum = nc;
      }
      sh_misc[0] = cb2; sh_misc[1] = abv;
    }
    __syncthreads();
    const unsigned cb = sh_misc[0], above = sh_misc[1];
    __syncthreads();
    h1[tid] = 0;
    __syncthreads();
#pragma unroll
    for (int i = 0; i < 8; ++i)
#pragma unroll
      for (int j = 0; j < 4; ++j)
        if ((sb[i][j] >> 24) == cb) atomicAdd(&h1[(sb[i][j] >> 16) & 0xFFu], 1u);
    __syncthreads();
    if (tid == 0) {
      unsigned cum = above, tb = cb << 8;
      for (int b = 255; b >= 0; --b) {
        cum += h1[b];
        if (cum >= 256u) { tb = (cb << 8) | (unsigned)b; break; }
      }
      const unsigned old = atomicMax(&ctr[2], tb);  // device-scope running bound
      sh_misc[2] = tb > old ? tb : old;
    }
    __syncthreads();
    const unsigned tb16 = sh_misc[2];

    // ---- candidate push: wave shuffle-scan + 4-entry serial base ----
    unsigned cnt = 0;
#pragma unroll
    for (int i = 0; i < 8; ++i)
#pragma unroll
      for (int j = 0; j < 4; ++j) cnt += ((sb[i][j] >> 16) >= tb16) ? 1u : 0u;
    const int lane = tid & 63, wv = tid >> 6;
    unsigned incl = cnt;
#pragma unroll
    for (int d = 1; d < 64; d <<= 1) {
      const unsigned nv = __shfl_up(incl, d, 64);
      if (lane >= d) incl += nv;
    }
    if (lane == 63) wsum[wv] = incl;
    __syncthreads();
    if (tid == 0) {
      unsigned run = 0;
#pragma unroll
      for (int w = 0; w < 4; ++w) { const unsigned c = wsum[w]; wsum[w] = run; run += c; }
      sh_misc[3] = atomicAdd(&ctr[0], run);
    }
    __syncthreads();
    unsigned pos = sh_misc[3] + wsum[wv] + incl - cnt;
#pragma unroll
    for (int i = 0; i < 8; ++i)
#pragma unroll
      for (int j = 0; j < 4; ++j) {
        if ((sb[i][j] >> 16) >= tb16) {
          if (pos < cap) {
            const unsigned idxv = ((unsigned)(n0 + ty * 8 + i) << 13)
                                | (unsigned)(m0 + h * 64 + tx * 4 + j);
            cand[pos] = make_uint2(sb[i][j], idxv);
          }
          ++pos;
        }
      }
    __syncthreads();  // h1/wsum/sh_misc reuse in next half
  }
}

// ---------------------------------------------------------------------------
// Tail: LDS-aggregated coarse(8b) + fine(8b) histograms -> threshold -> collect
// -> sort.
// ---------------------------------------------------------------------------
__global__ __launch_bounds__(256) void k_histc(const uint2* __restrict__ cand,
                                               const unsigned int* __restrict__ ctr,
                                               unsigned int cap,
                                               unsigned int* __restrict__ ghc) {
  __shared__ unsigned int lh[256];
  const int tid = threadIdx.x;
  lh[tid] = 0;
  __syncthreads();
  const unsigned n = min(ctr[0], cap);
  const unsigned stride = gridDim.x * blockDim.x;
  for (unsigned i = blockIdx.x * blockDim.x + tid; i < n; i += stride)
    atomicAdd(&lh[cand[i].x >> 24], 1u);
  __syncthreads();
  if (lh[tid]) atomicAdd(&ghc[tid], lh[tid]);
}

__global__ __launch_bounds__(256) void k_threshc(const unsigned int* __restrict__ ghc,
                                                 unsigned int* __restrict__ ctr) {
  __shared__ unsigned int g[256];
  const int tid = threadIdx.x;
  g[tid] = ghc[tid];
  __syncthreads();
  if (tid == 0) {
    unsigned cum = 0;
    for (int b = 255; b >= 0; --b) {
      cum += g[b];
      if (cum >= 256u) { ctr[4] = (unsigned)b; ctr[5] = cum - g[b]; break; }
    }
  }
}

__global__ __launch_bounds__(256) void k_histf(const uint2* __restrict__ cand,
                                               const unsigned int* __restrict__ ctr,
                                               unsigned int cap,
                                               unsigned int* __restrict__ ghf) {
  __shared__ unsigned int lh[256];
  const int tid = threadIdx.x;
  lh[tid] = 0;
  __syncthreads();
  const unsigned n = min(ctr[0], cap);
  const unsigned cb = ctr[4];
  const unsigned stride = gridDim.x * blockDim.x;
  for (unsigned i = blockIdx.x * blockDim.x + tid; i < n; i += stride) {
    const unsigned k = cand[i].x;
    if ((k >> 24) == cb) atomicAdd(&lh[(k >> 16) & 0xFFu], 1u);
  }
  __syncthreads();
  if (lh[tid]) atomicAdd(&ghf[tid], lh[tid]);
}

__global__ __launch_bounds__(256) void k_threshf(const unsigned int* __restrict__ ghf,
                                                 unsigned int* __restrict__ ctr) {
  __shared__ unsigned int g[256];
  const int tid = threadIdx.x;
  g[tid] = ghf[tid];
  __syncthreads();
  if (tid == 0) {
    const unsigned cb = ctr[4];
    unsigned cum = ctr[5], tb = cb << 8;
    for (int b = 255; b >= 0; --b) {
      cum += g[b];
      if (cum >= 256u) { tb = (cb << 8) | (unsigned)b; break; }
    }
    ctr[3] = tb;
  }
}

__global__ void k_collect(const uint2* __restrict__ cand,
                          unsigned int* __restrict__ ctr,
                          unsigned int cap, uint2* __restrict__ fin) {
  const unsigned n = min(ctr[0], cap);
  const unsigned tb = ctr[3];
  const unsigned stride = gridDim.x * blockDim.x;
  for (unsigned i = blockIdx.x * blockDim.x + threadIdx.x; i < n; i += stride) {
    const uint2 c = cand[i];
    if ((c.x >> 16) >= tb) {
      const unsigned p = atomicAdd(&ctr[1], 1u);
      if (p < FCAP) fin[p] = c;
    }
  }
}

// Sort: pack (key, ~idx) into u64, bitonic desc -> (key desc, idx asc) —
// exactly lax.top_k / np tie semantics on the f32 scores.
__global__ __launch_bounds__(256) void k_sort(const uint2* __restrict__ fin,
                                              const unsigned int* __restrict__ ctr,
                                              float* __restrict__ out) {
  __shared__ unsigned long long kk[FCAP];
  const int tid = threadIdx.x;
  const unsigned n = min(ctr[1], FCAP);
  unsigned np2 = 256;
  while (np2 < n) np2 <<= 1;
  for (unsigned i = tid; i < np2; i += 256) {
    if (i < n) {
      const uint2 c = fin[i];
      kk[i] = ((unsigned long long)c.x << 32) | (unsigned long long)(c.y ^ 0xFFFFFFFFu);
    } else {
      kk[i] = 0ull;
    }
  }
  __syncthreads();
  for (unsigned k2 = 2; k2 <= np2; k2 <<= 1) {
    for (unsigned j = k2 >> 1; j > 0; j >>= 1) {
      for (unsigned i = tid; i < np2; i += 256) {
        const unsigned l = i ^ j;
        if (l > i) {
          const unsigned long long ka = kk[i], kb = kk[l];
          const bool aBefore = ka > kb;
          const bool dsc = (i & k2) == 0;
          const bool sw = dsc ? !aBefore : aBefore;
          if (sw) { kk[i] = kb; kk[l] = ka; }
        }
      }
      __syncthreads();
    }
  }
  {
    const unsigned long long kv = kk[tid];
    const unsigned key = (unsigned)(kv >> 32);
    const unsigned ix  = ((unsigned)kv) ^ 0xFFFFFFFFu;
    out[tid]        = (float)(ix >> 13);      // ref_corr_indices
    out[256 + tid]  = (float)(ix & 8191u);    // src_corr_indices
    out[512 + tid]  = __uint_as_float(key);   // corr_scores (same f32 bits)
  }
}

// ---------------------------------------------------------------------------
extern "C" void kernel_launch(void* const* d_in, const int* in_sizes, int n_in,
                              void* d_out, int out_size, void* d_ws, size_t ws_size,
                              hipStream_t stream) {
  (void)in_sizes; (void)n_in; (void)out_size;
  const float* ref = (const float*)d_in[0];
  const float* src = (const float*)d_in[1];
  const float* c0  = (const float*)d_in[2];
  const float* c1  = (const float*)d_in[3];
  char* ws = (char*)d_ws;
  double* Sr = (double*)(ws + WS_SR);
  double* Sc = (double*)(ws + WS_SC);
  unsigned int* ctr = (unsigned int*)(ws + WS_CTR);
  unsigned int* ghc = (unsigned int*)(ws + WS_GHC);
  unsigned int* ghf = (unsigned int*)(ws + WS_GHF);
  uint2* fin  = (uint2*)(ws + WS_FINAL);
  uint2* cand = (uint2*)(ws + WS_CAND);
  const unsigned int cap = (ws_size > WS_CAND + 8)
      ? (unsigned int)std::min<size_t>((ws_size - WS_CAND) / 8, (size_t)(16u << 20))
      : 0u;

  hipMemsetAsync(d_ws, 0, (size_t)WS_FINAL, stream);  // Sr, Sc, ctr, ghc, ghf

  dim3 g1(Mm / BT, Nn / BT);
  k_pass1<<<g1, 256, 0, stream>>>(ref, src, Sr, Sc);
  k_recip<<<32, 256, 0, stream>>>(Sr, Sc);
  k_pass2<<<g1, 256, 0, stream>>>(ref, src, c0, c1, Sr, Sc, cand, ctr, cap);
  k_histc<<<256, 256, 0, stream>>>(cand, ctr, cap, ghc);
  k_threshc<<<1, 256, 0, stream>>>(ghc, ctr);
  k_histf<<<256, 256, 0, stream>>>(cand, ctr, cap, ghf);
  k_threshf<<<1, 256, 0, stream>>>(ghf, ctr);
  k_collect<<<256, 256, 0, stream>>>(cand, ctr, cap, fin);
  k_sort<<<1, 256, 0, stream>>>(fin, ctr, (float*)d_out);
}

// Round 12
// 2001.092 us; speedup vs baseline: 1.2916x; 1.2712x over previous
//
#include <hip/hip_runtime.h>
#include <algorithm>
#include <cstdint>

// Problem constants (fixed by setup_inputs)
#define Nn 8192
#define Mm 8192
#define Dd 512
#define Cc 128

#define BT  128  // tile (n and m) for both passes
#define TK  16   // k-chunk (load-bearing for numerics; do not change)

// RA ledger (gfx950, this session): (256,2) -> 128 VGPR deterministic,
// no spills when live < 128. All other settings under-allocate (spill thrash).
#define KERNEL_OCC __launch_bounds__(256, 2)

// ---- workspace layout (bytes); ws_size measured = 256 MiB exactly (R11:
// poison fill WRITE_SIZE = 262144 KB) ----
#define WS_SR    0ull         // double[8192]
#define WS_SC    65536ull     // double[8192]
#define WS_CTR   131072ull    // uint[16]: 0=cand_n 1=fin_n 2=run_tb16 3=tb16 4=cbin 5=above
#define WS_GHC   131136ull    // uint[256] coarse hist
#define WS_GHF   132160ull    // uint[256] fine hist
#define WS_FINAL 133184ull    // uint2[4096]
#define WS_CAND  165952ull    // uint2[3145728] = 24 MiB (R11 measured 1.53M used)
#define WS_INNER 25331776ull  // float[7296*8192] = 239 MB stored inner rows
#define RSTORE   7296         // 57 of 64 block-rows stored
#define WS_NEED  (WS_INNER + (size_t)RSTORE * Mm * 4ull)   // 264407104
#define FCAP     4096u

// column mapping (8 cols over 128): {tx*4..+3} and {64+tx*4..+3}
__device__ __forceinline__ int jcol(int tx, int j) {
  return (j < 4) ? tx * 4 + j : 64 + tx * 4 + (j - 4);
}

// ---------------------------------------------------------------------------
// THE inner GEMM (256 thr, 8x8/thread, 128^2 tile): two-level accumulation
// with i-split, register prefetch. ~73-80% of fp32 roofline in k_pass1.
// Per-element chain: fresh 16-fma chain per 16-k chunk (kk order), one add
// into acc2, chunks in order. Proven absmax=0 (R4-R11).
// ---------------------------------------------------------------------------
__device__ __forceinline__ void inner_gemm(const float* __restrict__ A,
                                           const float* __restrict__ B,
                                           int n0, int m0, int tid,
                                           float (*SA)[BT], float (*SB)[BT],
                                           float acc2[8][8]) {
  const int tx = tid & 15, ty = tid >> 4;
  const int lrow = tid >> 1;       // 0..127
  const int lk8  = (tid & 1) * 8;  // 0 or 8
  const float* Ap = A + (size_t)(n0 + lrow) * Dd + lk8;
  const float* Bp = B + (size_t)(m0 + lrow) * Dd + lk8;

#pragma unroll
  for (int i = 0; i < 8; ++i)
#pragma unroll
    for (int j = 0; j < 8; ++j) acc2[i][j] = 0.0f;

  float4 pa0 = *(const float4*)(Ap);
  float4 pa1 = *(const float4*)(Ap + 4);
  float4 pb0 = *(const float4*)(Bp);
  float4 pb1 = *(const float4*)(Bp + 4);

  for (int k0 = 0; k0 < Dd; k0 += TK) {
    __syncthreads();
    {
      const float ar[8] = {pa0.x,pa0.y,pa0.z,pa0.w,pa1.x,pa1.y,pa1.z,pa1.w};
      const float br[8] = {pb0.x,pb0.y,pb0.z,pb0.w,pb1.x,pb1.y,pb1.z,pb1.w};
#pragma unroll
      for (int s = 0; s < 8; ++s) { SA[lk8 + s][lrow] = ar[s]; SB[lk8 + s][lrow] = br[s]; }
    }
    if (k0 + TK < Dd) {  // prefetch flies during compute
      pa0 = *(const float4*)(Ap + k0 + TK);
      pa1 = *(const float4*)(Ap + k0 + TK + 4);
      pb0 = *(const float4*)(Bp + k0 + TK);
      pb1 = *(const float4*)(Bp + k0 + TK + 4);
    }
    __syncthreads();
#pragma unroll
    for (int h = 0; h < 2; ++h) {
      float t[4][8];
#pragma unroll
      for (int i = 0; i < 4; ++i)
#pragma unroll
        for (int j = 0; j < 8; ++j) t[i][j] = 0.0f;
#pragma unroll
      for (int kk = 0; kk < TK; ++kk) {
        const float4 av  = *(const float4*)&SA[kk][ty * 8 + h * 4];
        const float4 bv0 = *(const float4*)&SB[kk][tx * 4];
        const float4 bv1 = *(const float4*)&SB[kk][64 + tx * 4];
        const float a[4] = {av.x, av.y, av.z, av.w};
        const float b[8] = {bv0.x,bv0.y,bv0.z,bv0.w,bv1.x,bv1.y,bv1.z,bv1.w};
#pragma unroll
        for (int i = 0; i < 4; ++i)
#pragma unroll
          for (int j = 0; j < 8; ++j) t[i][j] = fmaf(a[i], b[j], t[i][j]);
      }
#pragma unroll
      for (int i = 0; i < 4; ++i)
#pragma unroll
        for (int j = 0; j < 8; ++j) acc2[h * 4 + i][j] += t[i][j];
    }
  }
}

// ---------------------------------------------------------------------------
// Pass 1: inner GEMM -> (store rows < RSTORE when STORE) -> exp sums (f64).
// ---------------------------------------------------------------------------
template<bool STORE>
__global__ KERNEL_OCC void k_pass1(const float* __restrict__ A,
                                   const float* __restrict__ B,
                                   double* __restrict__ Sr,
                                   double* __restrict__ Sc,
                                   float* __restrict__ inner) {
  __shared__ float SA[TK][BT];
  __shared__ float SB[TK][BT];
  __shared__ double csum[BT];
  const int tid = threadIdx.x;
  const int tx = tid & 15, ty = tid >> 4;
  const int n0 = blockIdx.y * BT, m0 = blockIdx.x * BT;

  float acc2[8][8];
  inner_gemm(A, B, n0, m0, tid, SA, SB, acc2);

  if (STORE && n0 < RSTORE) {
#pragma unroll
    for (int i = 0; i < 8; ++i) {
      float* rowp = inner + (size_t)(n0 + ty * 8 + i) * Mm + m0;
      *(float4*)(rowp + tx * 4)      = make_float4(acc2[i][0], acc2[i][1], acc2[i][2], acc2[i][3]);
      *(float4*)(rowp + 64 + tx * 4) = make_float4(acc2[i][4], acc2[i][5], acc2[i][6], acc2[i][7]);
    }
  }

  if (tid < BT) csum[tid] = 0.0;
  __syncthreads();

  float cp[8];
#pragma unroll
  for (int j = 0; j < 8; ++j) cp[j] = 0.0f;

#pragma unroll
  for (int i = 0; i < 8; ++i) {
    float r = 0.0f;
#pragma unroll
    for (int j = 0; j < 8; ++j) {
      const float e = expf(2.0f * acc2[i][j] - 2.0f);
      r += e;
      cp[j] += e;
    }
    double v = (double)r;
    v += __shfl_xor(v, 1, 16);
    v += __shfl_xor(v, 2, 16);
    v += __shfl_xor(v, 4, 16);
    v += __shfl_xor(v, 8, 16);
    if (tx == 0) atomicAdd(&Sr[n0 + ty * 8 + i], v);
  }
#pragma unroll
  for (int j = 0; j < 8; ++j) {
    double v = (double)cp[j];
    v += __shfl_xor(v, 16, 64);
    v += __shfl_xor(v, 32, 64);
    if ((tid & 63) < 16) atomicAdd(&csum[jcol(tx, j)], v);
  }
  __syncthreads();
  if (tid < BT) atomicAdd(&Sc[m0 + tid], csum[tid]);
}

// ---------------------------------------------------------------------------
__global__ void k_recip(double* __restrict__ Sr, double* __restrict__ Sc) {
  const int i = blockIdx.x * 256 + threadIdx.x;
  if (i < Nn) Sr[i] = 1.0 / Sr[i];
  if (i < Mm) Sc[i] = 1.0 / Sc[i];
}

// ---------------------------------------------------------------------------
// Pass 2: RELOAD=true reads the stored acc2 bits (skips the inner GEMM);
// RELOAD=false recomputes it (R11-proven path). Overlap GEMM + f64 epilogue +
// two-level histogram threshold + candidate push, in two 128x64 column halves.
// Per-element FP chains identical to R11 -> same score bits -> absmax 0.
// ---------------------------------------------------------------------------
template<bool RELOAD>
__global__ KERNEL_OCC void k_pass2(
    const float* __restrict__ A, const float* __restrict__ B,
    const float* __restrict__ C0, const float* __restrict__ C1,
    const double* __restrict__ invSr, const double* __restrict__ invSc,
    const float* __restrict__ inner, int yoff,
    uint2* __restrict__ cand, unsigned int* __restrict__ ctr, unsigned int cap) {
  __shared__ float SA[TK][BT];
  __shared__ float SB[TK][BT];
  __shared__ unsigned int h1[256];
  __shared__ unsigned int wsum[4];
  __shared__ unsigned int sh_misc[4];
  __shared__ double dsr[BT];
  __shared__ double dsc[BT];
  const int tid = threadIdx.x;
  const int tx = tid & 15, ty = tid >> 4;
  const int n0 = (blockIdx.y + yoff) * BT, m0 = blockIdx.x * BT;

  // f64 normalizers -> LDS once (same bits); first use is after barriers
  if (tid < BT) dsr[tid] = invSr[n0 + tid];
  else          dsc[tid - BT] = invSc[m0 + tid - BT];

  float acc2[8][8];
  if (!RELOAD) {
    inner_gemm(A, B, n0, m0, tid, SA, SB, acc2);
  }

  const int frow = tid >> 4;        // 0..15 overlap staging row
  const int fn   = (tid & 15) * 8;  // 0..120 staging col

#pragma unroll
  for (int h = 0; h < 2; ++h) {
    // ---- overlap GEMM for column half h (cols h*64 + tx*4 ..+3) ----
    float ov[8][4];
#pragma unroll
    for (int i = 0; i < 8; ++i)
#pragma unroll
      for (int j = 0; j < 4; ++j) ov[i][j] = 0.0f;
    for (int c0i = 0; c0i < Cc; c0i += TK) {
      __syncthreads();
      *(float4*)&SA[frow][fn]     = *(const float4*)(C0 + (size_t)(c0i + frow) * Nn + n0 + fn);
      *(float4*)&SA[frow][fn + 4] = *(const float4*)(C0 + (size_t)(c0i + frow) * Nn + n0 + fn + 4);
      *(float4*)&SB[frow][fn]     = *(const float4*)(C1 + (size_t)(c0i + frow) * Mm + m0 + fn);
      *(float4*)&SB[frow][fn + 4] = *(const float4*)(C1 + (size_t)(c0i + frow) * Mm + m0 + fn + 4);
      __syncthreads();
#pragma unroll
      for (int g = 0; g < 2; ++g) {
        float th[4][4];
#pragma unroll
        for (int i = 0; i < 4; ++i)
#pragma unroll
          for (int j = 0; j < 4; ++j) th[i][j] = 0.0f;
#pragma unroll
        for (int kk = 0; kk < TK; ++kk) {
          const float4 av = *(const float4*)&SA[kk][ty * 8 + g * 4];
          const float4 bv = *(const float4*)&SB[kk][h * 64 + tx * 4];
          const float a[4] = {av.x, av.y, av.z, av.w};
          const float b[4] = {bv.x, bv.y, bv.z, bv.w};
#pragma unroll
          for (int i = 0; i < 4; ++i)
#pragma unroll
            for (int j = 0; j < 4; ++j) th[i][j] = fmaf(a[i], b[j], th[i][j]);
        }
#pragma unroll
        for (int i = 0; i < 4; ++i)
#pragma unroll
          for (int j = 0; j < 4; ++j) ov[g * 4 + i][j] += th[i][j];
      }
    }

    // ---- acc bits for this half: reload stored f32 or slice recompute ----
    float acch[8][4];
    if (RELOAD) {
#pragma unroll
      for (int i = 0; i < 8; ++i)
        *(float4*)&acch[i][0] =
            *(const float4*)(inner + (size_t)(n0 + ty * 8 + i) * Mm + m0 + h * 64 + tx * 4);
    } else {
#pragma unroll
      for (int i = 0; i < 8; ++i)
#pragma unroll
        for (int j = 0; j < 4; ++j) acch[i][j] = acc2[i][h * 4 + j];
    }

    // ---- f64 score -> f32 key bits ----
    unsigned int sb[8][4];
#pragma unroll
    for (int i = 0; i < 8; ++i)
#pragma unroll
      for (int j = 0; j < 4; ++j) {
        const double e = exp(2.0 * (double)acch[i][j] - 2.0);
        const double s = e * e * dsr[ty * 8 + i] * dsc[h * 64 + tx * 4 + j] * (double)ov[i][j];
        sb[i][j] = __float_as_uint((float)s);  // s > 0 -> monotone bits
      }

    // ---- two-level (8+8 bit) histogram threshold over this half (8192) ----
    __syncthreads();
    h1[tid] = 0;
    __syncthreads();
#pragma unroll
    for (int i = 0; i < 8; ++i)
#pragma unroll
      for (int j = 0; j < 4; ++j) atomicAdd(&h1[sb[i][j] >> 24], 1u);
    __syncthreads();
    if (tid == 0) {
      unsigned cum = 0, cb2 = 0, abv = 0;
      for (int b = 255; b >= 0; --b) {
        const unsigned nc = cum + h1[b];
        if (nc >= 256u) { cb2 = (unsigned)b; abv = cum; break; }
        cum = nc;
      }
      sh_misc[0] = cb2; sh_misc[1] = abv;
    }
    __syncthreads();
    const unsigned cb = sh_misc[0], above = sh_misc[1];
    __syncthreads();
    h1[tid] = 0;
    __syncthreads();
#pragma unroll
    for (int i = 0; i < 8; ++i)
#pragma unroll
      for (int j = 0; j < 4; ++j)
        if ((sb[i][j] >> 24) == cb) atomicAdd(&h1[(sb[i][j] >> 16) & 0xFFu], 1u);
    __syncthreads();
    if (tid == 0) {
      unsigned cum = above, tb = cb << 8;
      for (int b = 255; b >= 0; --b) {
        cum += h1[b];
        if (cum >= 256u) { tb = (cb << 8) | (unsigned)b; break; }
      }
      const unsigned old = atomicMax(&ctr[2], tb);  // device-scope running bound
      sh_misc[2] = tb > old ? tb : old;
    }
    __syncthreads();
    const unsigned tb16 = sh_misc[2];

    // ---- candidate push: wave shuffle-scan + 4-entry serial base ----
    unsigned cnt = 0;
#pragma unroll
    for (int i = 0; i < 8; ++i)
#pragma unroll
      for (int j = 0; j < 4; ++j) cnt += ((sb[i][j] >> 16) >= tb16) ? 1u : 0u;
    const int lane = tid & 63, wv = tid >> 6;
    unsigned incl = cnt;
#pragma unroll
    for (int d = 1; d < 64; d <<= 1) {
      const unsigned nv = __shfl_up(incl, d, 64);
      if (lane >= d) incl += nv;
    }
    if (lane == 63) wsum[wv] = incl;
    __syncthreads();
    if (tid == 0) {
      unsigned run = 0;
#pragma unroll
      for (int w = 0; w < 4; ++w) { const unsigned c = wsum[w]; wsum[w] = run; run += c; }
      sh_misc[3] = atomicAdd(&ctr[0], run);
    }
    __syncthreads();
    unsigned pos = sh_misc[3] + wsum[wv] + incl - cnt;
#pragma unroll
    for (int i = 0; i < 8; ++i)
#pragma unroll
      for (int j = 0; j < 4; ++j) {
        if ((sb[i][j] >> 16) >= tb16) {
          if (pos < cap) {
            const unsigned idxv = ((unsigned)(n0 + ty * 8 + i) << 13)
                                | (unsigned)(m0 + h * 64 + tx * 4 + j);
            cand[pos] = make_uint2(sb[i][j], idxv);
          }
          ++pos;
        }
      }
    __syncthreads();  // h1/wsum/sh_misc reuse in next half
  }
}

// ---------------------------------------------------------------------------
// Tail: LDS-aggregated coarse(8b) + fine(8b) histograms -> threshold -> collect
// -> sort.
// ---------------------------------------------------------------------------
__global__ __launch_bounds__(256) void k_histc(const uint2* __restrict__ cand,
                                               const unsigned int* __restrict__ ctr,
                                               unsigned int cap,
                                               unsigned int* __restrict__ ghc) {
  __shared__ unsigned int lh[256];
  const int tid = threadIdx.x;
  lh[tid] = 0;
  __syncthreads();
  const unsigned n = min(ctr[0], cap);
  const unsigned stride = gridDim.x * blockDim.x;
  for (unsigned i = blockIdx.x * blockDim.x + tid; i < n; i += stride)
    atomicAdd(&lh[cand[i].x >> 24], 1u);
  __syncthreads();
  if (lh[tid]) atomicAdd(&ghc[tid], lh[tid]);
}

__global__ __launch_bounds__(256) void k_threshc(const unsigned int* __restrict__ ghc,
                                                 unsigned int* __restrict__ ctr) {
  __shared__ unsigned int g[256];
  const int tid = threadIdx.x;
  g[tid] = ghc[tid];
  __syncthreads();
  if (tid == 0) {
    unsigned cum = 0;
    for (int b = 255; b >= 0; --b) {
      cum += g[b];
      if (cum >= 256u) { ctr[4] = (unsigned)b; ctr[5] = cum - g[b]; break; }
    }
  }
}

__global__ __launch_bounds__(256) void k_histf(const uint2* __restrict__ cand,
                                               const unsigned int* __restrict__ ctr,
                                               unsigned int cap,
                                               unsigned int* __restrict__ ghf) {
  __shared__ unsigned int lh[256];
  const int tid = threadIdx.x;
  lh[tid] = 0;
  __syncthreads();
  const unsigned n = min(ctr[0], cap);
  const unsigned cb = ctr[4];
  const unsigned stride = gridDim.x * blockDim.x;
  for (unsigned i = blockIdx.x * blockDim.x + tid; i < n; i += stride) {
    const unsigned k = cand[i].x;
    if ((k >> 24) == cb) atomicAdd(&lh[(k >> 16) & 0xFFu], 1u);
  }
  __syncthreads();
  if (lh[tid]) atomicAdd(&ghf[tid], lh[tid]);
}

__global__ __launch_bounds__(256) void k_threshf(const unsigned int* __restrict__ ghf,
                                                 unsigned int* __restrict__ ctr) {
  __shared__ unsigned int g[256];
  const int tid = threadIdx.x;
  g[tid] = ghf[tid];
  __syncthreads();
  if (tid == 0) {
    const unsigned cb = ctr[4];
    unsigned cum = ctr[5], tb = cb << 8;
    for (int b = 255; b >= 0; --b) {
      cum += g[b];
      if (cum >= 256u) { tb = (cb << 8) | (unsigned)b; break; }
    }
    ctr[3] = tb;
  }
}

__global__ void k_collect(const uint2* __restrict__ cand,
                          unsigned int* __restrict__ ctr,
                          unsigned int cap, uint2* __restrict__ fin) {
  const unsigned n = min(ctr[0], cap);
  const unsigned tb = ctr[3];
  const unsigned stride = gridDim.x * blockDim.x;
  for (unsigned i = blockIdx.x * blockDim.x + threadIdx.x; i < n; i += stride) {
    const uint2 c = cand[i];
    if ((c.x >> 16) >= tb) {
      const unsigned p = atomicAdd(&ctr[1], 1u);
      if (p < FCAP) fin[p] = c;
    }
  }
}

// Sort: pack (key, ~idx) into u64, bitonic desc -> (key desc, idx asc) —
// exactly lax.top_k / np tie semantics on the f32 scores.
__global__ __launch_bounds__(256) void k_sort(const uint2* __restrict__ fin,
                                              const unsigned int* __restrict__ ctr,
                                              float* __restrict__ out) {
  __shared__ unsigned long long kk[FCAP];
  const int tid = threadIdx.x;
  const unsigned n = min(ctr[1], FCAP);
  unsigned np2 = 256;
  while (np2 < n) np2 <<= 1;
  for (unsigned i = tid; i < np2; i += 256) {
    if (i < n) {
      const uint2 c = fin[i];
      kk[i] = ((unsigned long long)c.x << 32) | (unsigned long long)(c.y ^ 0xFFFFFFFFu);
    } else {
      kk[i] = 0ull;
    }
  }
  __syncthreads();
  for (unsigned k2 = 2; k2 <= np2; k2 <<= 1) {
    for (unsigned j = k2 >> 1; j > 0; j >>= 1) {
      for (unsigned i = tid; i < np2; i += 256) {
        const unsigned l = i ^ j;
        if (l > i) {
          const unsigned long long ka = kk[i], kb = kk[l];
          const bool aBefore = ka > kb;
          const bool dsc = (i & k2) == 0;
          const bool sw = dsc ? !aBefore : aBefore;
          if (sw) { kk[i] = kb; kk[l] = ka; }
        }
      }
      __syncthreads();
    }
  }
  {
    const unsigned long long kv = kk[tid];
    const unsigned key = (unsigned)(kv >> 32);
    const unsigned ix  = ((unsigned)kv) ^ 0xFFFFFFFFu;
    out[tid]        = (float)(ix >> 13);      // ref_corr_indices
    out[256 + tid]  = (float)(ix & 8191u);    // src_corr_indices
    out[512 + tid]  = __uint_as_float(key);   // corr_scores (same f32 bits)
  }
}

// ---------------------------------------------------------------------------
extern "C" void kernel_launch(void* const* d_in, const int* in_sizes, int n_in,
                              void* d_out, int out_size, void* d_ws, size_t ws_size,
                              hipStream_t stream) {
  (void)in_sizes; (void)n_in; (void)out_size;
  const float* ref = (const float*)d_in[0];
  const float* src = (const float*)d_in[1];
  const float* c0  = (const float*)d_in[2];
  const float* c1  = (const float*)d_in[3];
  char* ws = (char*)d_ws;
  double* Sr = (double*)(ws + WS_SR);
  double* Sc = (double*)(ws + WS_SC);
  unsigned int* ctr = (unsigned int*)(ws + WS_CTR);
  unsigned int* ghc = (unsigned int*)(ws + WS_GHC);
  unsigned int* ghf = (unsigned int*)(ws + WS_GHF);
  uint2* fin   = (uint2*)(ws + WS_FINAL);
  uint2* cand  = (uint2*)(ws + WS_CAND);
  float* inner = (float*)(ws + WS_INNER);

  const bool store = ws_size >= (size_t)WS_NEED;
  unsigned int cap;
  if (store) {
    cap = (unsigned int)((WS_INNER - WS_CAND) / 8);   // 3,145,728 (2x observed)
  } else {
    cap = (ws_size > WS_CAND + 8)
        ? (unsigned int)std::min<size_t>((ws_size - WS_CAND) / 8, (size_t)(16u << 20))
        : 0u;
  }

  hipMemsetAsync(d_ws, 0, (size_t)WS_FINAL, stream);  // Sr, Sc, ctr, ghc, ghf

  dim3 g1(Mm / BT, Nn / BT);
  if (store) {
    k_pass1<true><<<g1, 256, 0, stream>>>(ref, src, Sr, Sc, inner);
    k_recip<<<32, 256, 0, stream>>>(Sr, Sc);
    dim3 gre(Mm / BT, RSTORE / BT);            // 64 x 57 reload blocks
    dim3 grc(Mm / BT, (Nn - RSTORE) / BT);     // 64 x 7 recompute blocks
    k_pass2<true><<<gre, 256, 0, stream>>>(ref, src, c0, c1, Sr, Sc, inner, 0, cand, ctr, cap);
    k_pass2<false><<<grc, 256, 0, stream>>>(ref, src, c0, c1, Sr, Sc, nullptr, RSTORE / BT, cand, ctr, cap);
  } else {
    k_pass1<false><<<g1, 256, 0, stream>>>(ref, src, Sr, Sc, nullptr);
    k_recip<<<32, 256, 0, stream>>>(Sr, Sc);
    k_pass2<false><<<g1, 256, 0, stream>>>(ref, src, c0, c1, Sr, Sc, nullptr, 0, cand, ctr, cap);
  }
  k_histc<<<256, 256, 0, stream>>>(cand, ctr, cap, ghc);
  k_threshc<<<1, 256, 0, stream>>>(ghc, ctr);
  k_histf<<<256, 256, 0, stream>>>(cand, ctr, cap, ghf);
  k_threshf<<<1, 256, 0, stream>>>(ghf, ctr);
  k_collect<<<256, 256, 0, stream>>>(cand, ctr, cap, fin);
  k_sort<<<1, 256, 0, stream>>>(fin, ctr, (float*)d_out);
}